// Round 2
// baseline (269.596 us; speedup 1.0000x reference)
//
#include <hip/hip_runtime.h>
#include <stdint.h>

// out[M,N] = x[M,K] @ dequant(W_q_packed)[K,N] + bias[N]
// M=N=K=4096, 4-bit nibbles packed 8/int32 along K, GROUP=128.
// R7: counted-vmcnt pipeline (T4). Per K-tile: {ds_read ALL fragments
// (interleaved by compiler under MFMA quads) -> lgkmcnt(0)+barrier (buffer
// dead) -> stage tile kt+2 into SAME buffer -> vmcnt(8) (waits only tile
// kt+1's loads, issued a full iteration earlier; kt+2's 8 stay in flight
// across the barrier) -> barrier}. vmcnt never 0 in main loop; 2 barriers
// per K-tile instead of 8. bv[4][2] holds all B-fragments (no re-read).
// LDS 128KB dbuf, zero-conflict XOR-cell layout. XCD swizzle: each XCD owns
// 2 B-panels (4MB = its L2), sweeps 16 M-tiles.

#define M_DIM 4096
#define N_DIM 4096
#define K_DIM 4096
#define NT (K_DIM / 64)

typedef __attribute__((ext_vector_type(8))) short short8;
typedef __attribute__((ext_vector_type(4))) float f32x4;

__device__ __forceinline__ unsigned short f2bf(float f) {
  uint32_t u = __builtin_bit_cast(uint32_t, f);
  u += 0x7fffu + ((u >> 16) & 1u);   // round-to-nearest-even
  return (unsigned short)(u >> 16);
}

// ---------- kernel 1: fused prep (unchanged) ----------
// blocks [0,2048): x fp32 -> bf16 (ushort8 stores).
// blocks [2048,3072): dequant + transpose -> W^T (N x K) bf16.
__global__ __launch_bounds__(256) void prep_kernel(const float* __restrict__ x,
                                                   unsigned short* __restrict__ xb,
                                                   const int* __restrict__ Wq,
                                                   const float* __restrict__ scales,
                                                   const float* __restrict__ zeros,
                                                   unsigned short* __restrict__ wt) {
  __shared__ uint4 Ts[32 * 64];  // 32 KB (dequant slice only)
  const int tid = threadIdx.x;
  if (blockIdx.x < 2048) {
    const int total = (M_DIM * K_DIM) / 8;   // 2M ushort8
    const float4* x4 = (const float4*)x;
    uint4* o8 = (uint4*)xb;
#pragma unroll
    for (int p = 0; p < 4; ++p) {
      int i = (p * 2048 + blockIdx.x) * 256 + tid;
      if (i < total) {
        float4 a = x4[2 * i], b = x4[2 * i + 1];
        uint4 o;
        o.x = (uint32_t)f2bf(a.x) | ((uint32_t)f2bf(a.y) << 16);
        o.y = (uint32_t)f2bf(a.z) | ((uint32_t)f2bf(a.w) << 16);
        o.z = (uint32_t)f2bf(b.x) | ((uint32_t)f2bf(b.y) << 16);
        o.w = (uint32_t)f2bf(b.z) | ((uint32_t)f2bf(b.w) << 16);
        o8[i] = o;
      }
    }
    return;
  }
  const int blk = blockIdx.x - 2048;
  const int n0 = (blk & 127) * 32;        // N/32 = 128 tiles
  const int gk0 = (blk >> 7) * 64;        // (K/8)/64 = 8 tiles

#pragma unroll
  for (int p = 0; p < 8; ++p) {
    int e = p * 256 + tid;
    int n_l = e & 31;
    int gk_l = e >> 5;
    int gk = gk0 + gk_l;
    int n = n0 + n_l;
    int g = gk >> 4;                // group = (gk*8)/128
    uint32_t q = (uint32_t)Wq[gk * N_DIM + n];
    float s = scales[g * N_DIM + n];
    float z = zeros[g * N_DIM + n];
    unsigned short b[8];
#pragma unroll
    for (int j = 0; j < 8; ++j) {
      float f = ((float)((q >> (4 * j)) & 15u) - z) * s;
      b[j] = f2bf(f);
    }
    uint4 cell;
    cell.x = (uint32_t)b[0] | ((uint32_t)b[1] << 16);
    cell.y = (uint32_t)b[2] | ((uint32_t)b[3] << 16);
    cell.z = (uint32_t)b[4] | ((uint32_t)b[5] << 16);
    cell.w = (uint32_t)b[6] | ((uint32_t)b[7] << 16);
    Ts[n_l * 64 + (gk_l ^ (n_l & 7))] = cell;
  }
  __syncthreads();
  uint4* dst = (uint4*)wt;
#pragma unroll
  for (int p = 0; p < 8; ++p) {
    int n_l = p * 4 + (tid >> 6);
    int gk_l = tid & 63;
    uint4 cell = Ts[n_l * 64 + (gk_l ^ (n_l & 7))];
    dst[(size_t)(n0 + n_l) * (K_DIM / 8) + (gk0 + gk_l)] = cell;
  }
}

// ---------- kernel 2: bf16 GEMM, C = A @ Bt^T + bias ----------
// 256x256 tile, 8 waves (wm 0..1, wn 0..3), each wave 128x64 output =
// acc[8][4] of 16x16x32 MFMA. BK=64, double-buffered 2x(32+32)KB LDS.
// LDS cell layout (16B cells): cell = row*8 + (kc ^ (row&7)); staging writes
// lane-linear dest with pre-swizzled global source (both-sides involution).

// stage one 256x64 bf16 tile (A or B) = 4 collective global_load_lds
#define STAGE4(DST, SRC)                                                         \
  {                                                                              \
    _Pragma("unroll") for (int j = 0; j < 4; ++j)                                \
        __builtin_amdgcn_global_load_lds(                                        \
            (const __attribute__((address_space(1))) void*)((SRC) +              \
                                                            (size_t)j * 64 * K_DIM), \
            (__attribute__((address_space(3))) void*)((DST) + tid + j * 512),    \
            16, 0, 0);                                                           \
  }

#define LOADA(QM)                                                                \
  {                                                                              \
    _Pragma("unroll") for (int mi = 0; mi < 4; ++mi) {                           \
      af[mi][0] = ASb[a_base + ((QM) * 4 + mi) * 128 + kx0];                     \
      af[mi][1] = ASb[a_base + ((QM) * 4 + mi) * 128 + kx1];                     \
    }                                                                            \
  }

// all 4 column-blocks of B held in regs for the whole K-tile
#define LOADBALL                                                                 \
  {                                                                              \
    _Pragma("unroll") for (int nn = 0; nn < 4; ++nn) {                           \
      bv[nn][0] = BSb[b_base + nn * 128 + kx0];                                  \
      bv[nn][1] = BSb[b_base + nn * 128 + kx1];                                  \
    }                                                                            \
  }

#define MFMA16(QM, QN)                                                           \
  {                                                                              \
    __builtin_amdgcn_s_setprio(1);                                               \
    _Pragma("unroll") for (int mi = 0; mi < 4; ++mi)                             \
        _Pragma("unroll") for (int ni = 0; ni < 2; ++ni) {                       \
      acc[(QM) * 4 + mi][(QN) * 2 + ni] = __builtin_amdgcn_mfma_f32_16x16x32_bf16( \
          af[mi][0], bv[(QN) * 2 + ni][0], acc[(QM) * 4 + mi][(QN) * 2 + ni], 0, 0, 0); \
      acc[(QM) * 4 + mi][(QN) * 2 + ni] = __builtin_amdgcn_mfma_f32_16x16x32_bf16( \
          af[mi][1], bv[(QN) * 2 + ni][1], acc[(QM) * 4 + mi][(QN) * 2 + ni], 0, 0, 0); \
    }                                                                            \
    __builtin_amdgcn_s_setprio(0);                                               \
  }

__global__ __launch_bounds__(512, 2) void gemm_bt_kernel(
    const unsigned short* __restrict__ A, const unsigned short* __restrict__ Bt,
    const float* __restrict__ bias, float* __restrict__ C) {
  __shared__ short8 As[2 * 2048];  // 64 KB (2 buffers x 256 rows x 8 cells)
  __shared__ short8 Bs[2 * 2048];  // 64 KB

  const int tid = threadIdx.x;
  const int lane = tid & 63;
  const int w = tid >> 6;      // 0..7
  const int wm = w >> 2;       // 0..1
  const int wn = w & 3;        // 0..3

  // XCD swizzle: 256 blocks; xcd owns nt in {2*xcd, 2*xcd+1} (4MB of B = L2)
  const int b = blockIdx.x;
  const int xcd = b & 7;
  const int loc = b >> 3;              // 0..31
  const int nt = xcd * 2 + (loc & 1);  // 0..15
  const int mt = loc >> 1;             // 0..15
  const int m0 = mt * 256;
  const int n0 = nt * 256;

  // staging: thread covers cells tid + j*512 (j=0..3); decode cell -> (row,kc)
  const int srow = tid >> 3;                       // base row 0..63 (+64 per j)
  const int skc = (tid & 7) ^ (srow & 7);          // invariant across j (row step 64)
  const unsigned short* Ablk = A + (size_t)m0 * K_DIM + (size_t)srow * K_DIM + skc * 8;
  const unsigned short* Bblk = Bt + (size_t)n0 * K_DIM + (size_t)srow * K_DIM + skc * 8;

  // fragment read addressing
  const int fr = lane & 15;            // row-low (A) / col-low (B)
  const int fc = lane >> 4;            // k-quarter 0..3
  const int frx = fr & 7;
  const int a_base = (wm * 128 + fr) * 8;
  const int b_base = (wn * 64 + fr) * 8;
  const int kx0 = fc ^ frx;            // k-step 0
  const int kx1 = (4 + fc) ^ frx;      // k-step 1

  f32x4 acc[8][4] = {};
  short8 af[4][2];
  short8 bv[4][2];

  // prologue: stage tile 0 -> buf0, tile 1 -> buf1; wait only tile 0 (vmcnt 8)
  STAGE4(As, Ablk);
  STAGE4(Bs, Bblk);
  STAGE4(As + 2048, Ablk + 64);
  STAGE4(Bs + 2048, Bblk + 64);
  asm volatile("s_waitcnt vmcnt(8)" ::: "memory");
  __builtin_amdgcn_sched_barrier(0);
  __builtin_amdgcn_s_barrier();

  for (int kt = 0; kt < NT; ++kt) {
    const int cur = kt & 1;
    const short8* ASb = As + cur * 2048;
    const short8* BSb = Bs + cur * 2048;

    // consume buf[cur] entirely into registers; compiler interleaves the
    // ds_reads under the MFMA quads (fine-grained lgkmcnt)
    LOADA(0);
    LOADBALL;
    MFMA16(0, 0);
    MFMA16(0, 1);
    LOADA(1);
    MFMA16(1, 1);
    MFMA16(1, 0);

    // buffer dead across all waves -> overwrite with tile kt+2
    asm volatile("s_waitcnt lgkmcnt(0)" ::: "memory");
    __builtin_amdgcn_sched_barrier(0);
    __builtin_amdgcn_s_barrier();
    if (kt + 2 < NT) {
      STAGE4(As + cur * 2048, Ablk + (size_t)(kt + 2) * 64);
      STAGE4(Bs + cur * 2048, Bblk + (size_t)(kt + 2) * 64);
      // wait only tile kt+1's 8 loads (issued a full iteration ago);
      // kt+2's 8 remain in flight across the barrier
      asm volatile("s_waitcnt vmcnt(8)" ::: "memory");
    } else {
      asm volatile("s_waitcnt vmcnt(0)" ::: "memory");
    }
    __builtin_amdgcn_sched_barrier(0);
    __builtin_amdgcn_s_barrier();
  }

  // epilogue: C/D layout col=lane&15, row=(lane>>4)*4+reg
  const int rr = (lane >> 4) * 4;
#pragma unroll
  for (int ni = 0; ni < 4; ++ni) {
    const int gn = n0 + wn * 64 + ni * 16 + fr;
    const float bvv = bias[gn];
#pragma unroll
    for (int mi = 0; mi < 8; ++mi) {
      const int gm = m0 + wm * 128 + mi * 16 + rr;
#pragma unroll
      for (int r = 0; r < 4; ++r)
        C[(size_t)(gm + r) * N_DIM + gn] = acc[mi][ni][r] + bvv;
    }
  }
}

extern "C" void kernel_launch(void* const* d_in, const int* in_sizes, int n_in,
                              void* d_out, int out_size, void* d_ws, size_t ws_size,
                              hipStream_t stream) {
  const float* x = (const float*)d_in[0];
  const int* wq = (const int*)d_in[1];
  const float* sc = (const float*)d_in[2];
  const float* zr = (const float*)d_in[3];
  const float* bias = (const float*)d_in[4];
  float* out = (float*)d_out;

  unsigned short* xb = (unsigned short*)d_ws;
  unsigned short* wt = (unsigned short*)((char*)d_ws + (size_t)M_DIM * K_DIM * 2);

  prep_kernel<<<dim3(3072), dim3(256), 0, stream>>>(x, xb, wq, sc, zr, wt);
  gemm_bt_kernel<<<dim3(256), dim3(512), 0, stream>>>(xb, wt, bias, out);
}

// Round 3
// 262.885 us; speedup vs baseline: 1.0255x; 1.0255x over previous
//
#include <hip/hip_runtime.h>
#include <stdint.h>

// out[M,N] = x[M,K] @ dequant(W_q_packed)[K,N] + bias[N]
// M=N=K=4096, 4-bit nibbles packed 8/int32 along K, GROUP=128.
// R8: true 8-phase fine interleave (T3+T4+T5), half-tile ring staging.
// 256x256 tile, BK=64, 8 waves; per wave output = 2x2 quadrants of 64x32
// fragments blocks (rows rb*128+wm*64+[0,64), cols cb*128+wn*32+[0,32)).
// 4 phases/K-tile, one quadrant each; per phase: vmcnt(6) -> ds_read frags
// -> stage ONE half-tile (2 global_load_lds) -> barrier -> lgkmcnt(0) ->
// setprio(1) 16xMFMA setprio(0) -> barrier. Halves die early (A0@P2, B0@P3)
// so tile kt+2's halves stage during kt's P3/P4: steady state 3 halves
// (6 loads) in flight, vmcnt never drains. All stage->read lags >=5 phases
// (cross-wave vmcnt+barrier chain), WAR checked per slot.
// LDS 128KB dbuf, zero-conflict XOR-cell layout. XCD swizzle: each XCD owns
// 2 B-panels (4MB = its L2), sweeps 16 M-tiles.

#define M_DIM 4096
#define N_DIM 4096
#define K_DIM 4096
#define NT (K_DIM / 64)

typedef __attribute__((ext_vector_type(8))) short short8;
typedef __attribute__((ext_vector_type(4))) float f32x4;

__device__ __forceinline__ unsigned short f2bf(float f) {
  uint32_t u = __builtin_bit_cast(uint32_t, f);
  u += 0x7fffu + ((u >> 16) & 1u);   // round-to-nearest-even
  return (unsigned short)(u >> 16);
}

// ---------- kernel 1: fused prep (unchanged) ----------
__global__ __launch_bounds__(256) void prep_kernel(const float* __restrict__ x,
                                                   unsigned short* __restrict__ xb,
                                                   const int* __restrict__ Wq,
                                                   const float* __restrict__ scales,
                                                   const float* __restrict__ zeros,
                                                   unsigned short* __restrict__ wt) {
  __shared__ uint4 Ts[32 * 64];  // 32 KB (dequant slice only)
  const int tid = threadIdx.x;
  if (blockIdx.x < 2048) {
    const int total = (M_DIM * K_DIM) / 8;   // 2M ushort8
    const float4* x4 = (const float4*)x;
    uint4* o8 = (uint4*)xb;
#pragma unroll
    for (int p = 0; p < 4; ++p) {
      int i = (p * 2048 + blockIdx.x) * 256 + tid;
      if (i < total) {
        float4 a = x4[2 * i], b = x4[2 * i + 1];
        uint4 o;
        o.x = (uint32_t)f2bf(a.x) | ((uint32_t)f2bf(a.y) << 16);
        o.y = (uint32_t)f2bf(a.z) | ((uint32_t)f2bf(a.w) << 16);
        o.z = (uint32_t)f2bf(b.x) | ((uint32_t)f2bf(b.y) << 16);
        o.w = (uint32_t)f2bf(b.z) | ((uint32_t)f2bf(b.w) << 16);
        o8[i] = o;
      }
    }
    return;
  }
  const int blk = blockIdx.x - 2048;
  const int n0 = (blk & 127) * 32;        // N/32 = 128 tiles
  const int gk0 = (blk >> 7) * 64;        // (K/8)/64 = 8 tiles

#pragma unroll
  for (int p = 0; p < 8; ++p) {
    int e = p * 256 + tid;
    int n_l = e & 31;
    int gk_l = e >> 5;
    int gk = gk0 + gk_l;
    int n = n0 + n_l;
    int g = gk >> 4;                // group = (gk*8)/128
    uint32_t q = (uint32_t)Wq[gk * N_DIM + n];
    float s = scales[g * N_DIM + n];
    float z = zeros[g * N_DIM + n];
    unsigned short b[8];
#pragma unroll
    for (int j = 0; j < 8; ++j) {
      float f = ((float)((q >> (4 * j)) & 15u) - z) * s;
      b[j] = f2bf(f);
    }
    uint4 cell;
    cell.x = (uint32_t)b[0] | ((uint32_t)b[1] << 16);
    cell.y = (uint32_t)b[2] | ((uint32_t)b[3] << 16);
    cell.z = (uint32_t)b[4] | ((uint32_t)b[5] << 16);
    cell.w = (uint32_t)b[6] | ((uint32_t)b[7] << 16);
    Ts[n_l * 64 + (gk_l ^ (n_l & 7))] = cell;
  }
  __syncthreads();
  uint4* dst = (uint4*)wt;
#pragma unroll
  for (int p = 0; p < 8; ++p) {
    int n_l = p * 4 + (tid >> 6);
    int gk_l = tid & 63;
    uint4 cell = Ts[n_l * 64 + (gk_l ^ (n_l & 7))];
    dst[(size_t)(n0 + n_l) * (K_DIM / 8) + (gk0 + gk_l)] = cell;
  }
}

// ---------- kernel 2: bf16 GEMM, C = A @ Bt^T + bias ----------
// LDS cell layout (16B cells): cell = row*8 + (kc ^ (row&7)); staging writes
// lane-linear dest with pre-swizzled global source (both-sides involution).
// A-half h = rows [h*128, h*128+128) of the 256-row tile = cells [h*1024,+1024).

// stage one 128-row half-tile: 2 collective global_load_lds per thread
#define STAGEH(DST, SRC)                                                        \
  {                                                                             \
    __builtin_amdgcn_global_load_lds(                                           \
        (const __attribute__((address_space(1))) void*)(SRC),                   \
        (__attribute__((address_space(3))) void*)((DST) + tid), 16, 0, 0);      \
    __builtin_amdgcn_global_load_lds(                                           \
        (const __attribute__((address_space(1))) void*)((SRC) + 64 * K_DIM),    \
        (__attribute__((address_space(3))) void*)((DST) + tid + 512), 16, 0, 0);\
  }

// af: 4 row-frags of the current rb (rows rb*128 + wm*64 + mi*16 + fr)
#define LOADAF(RB)                                                              \
  {                                                                             \
    _Pragma("unroll") for (int mi = 0; mi < 4; ++mi) {                          \
      af[mi][0] = ASb[(RB)*1024 + a_base + mi * 128 + kx0];                     \
      af[mi][1] = ASb[(RB)*1024 + a_base + mi * 128 + kx1];                     \
    }                                                                           \
  }

// bv: 2 col-frags of the current cb (rows cb*128 + wn*32 + ni*16 + fr)
#define LOADBV(CB)                                                              \
  {                                                                             \
    _Pragma("unroll") for (int ni = 0; ni < 2; ++ni) {                          \
      bv[ni][0] = BSb[(CB)*1024 + b_base + ni * 128 + kx0];                     \
      bv[ni][1] = BSb[(CB)*1024 + b_base + ni * 128 + kx1];                     \
    }                                                                           \
  }

#define MFMAQ(RB, CB)                                                           \
  {                                                                             \
    __builtin_amdgcn_s_setprio(1);                                              \
    _Pragma("unroll") for (int mi = 0; mi < 4; ++mi)                            \
        _Pragma("unroll") for (int ni = 0; ni < 2; ++ni) {                      \
      acc[(RB)*4 + mi][(CB)*2 + ni] = __builtin_amdgcn_mfma_f32_16x16x32_bf16(  \
          af[mi][0], bv[ni][0], acc[(RB)*4 + mi][(CB)*2 + ni], 0, 0, 0);        \
      acc[(RB)*4 + mi][(CB)*2 + ni] = __builtin_amdgcn_mfma_f32_16x16x32_bf16(  \
          af[mi][1], bv[ni][1], acc[(RB)*4 + mi][(CB)*2 + ni], 0, 0, 0);        \
    }                                                                           \
    __builtin_amdgcn_s_setprio(0);                                              \
  }

#define WAIT_VM6                                           \
  asm volatile("s_waitcnt vmcnt(6)" ::: "memory");         \
  __builtin_amdgcn_sched_barrier(0);

#define WAIT_LGKM0                                         \
  asm volatile("s_waitcnt lgkmcnt(0)" ::: "memory");       \
  __builtin_amdgcn_sched_barrier(0);

__global__ __launch_bounds__(512, 2) void gemm_bt_kernel(
    const unsigned short* __restrict__ A, const unsigned short* __restrict__ Bt,
    const float* __restrict__ bias, float* __restrict__ C) {
  __shared__ short8 As[2 * 2048];  // 64 KB (2 buffers x 256 rows x 8 cells)
  __shared__ short8 Bs[2 * 2048];  // 64 KB

  const int tid = threadIdx.x;
  const int lane = tid & 63;
  const int w = tid >> 6;      // 0..7
  const int wm = w >> 2;       // 0..1
  const int wn = w & 3;        // 0..3

  // XCD swizzle: 256 blocks; xcd owns nt in {2*xcd, 2*xcd+1} (4MB of B = L2)
  const int b = blockIdx.x;
  const int xcd = b & 7;
  const int loc = b >> 3;              // 0..31
  const int nt = xcd * 2 + (loc & 1);  // 0..15
  const int mt = loc >> 1;             // 0..15
  const int m0 = mt * 256;
  const int n0 = nt * 256;

  // staging addressing: thread covers cells tid (+512) within a half
  const int srow = tid >> 3;                       // local row 0..63 (+64 for j=1)
  const int skc = (tid & 7) ^ (srow & 7);          // row&7 invariant across +64
  const unsigned short* Asrc0 = A + (size_t)(m0 + srow) * K_DIM + skc * 8;
  const unsigned short* Asrc1 = Asrc0 + (size_t)128 * K_DIM;
  const unsigned short* Bsrc0 = Bt + (size_t)(n0 + srow) * K_DIM + skc * 8;
  const unsigned short* Bsrc1 = Bsrc0 + (size_t)128 * K_DIM;

  // fragment read addressing
  const int fr = lane & 15;            // row-low (A) / col-low (B)
  const int fc = lane >> 4;            // k-quarter 0..3
  const int frx = fr & 7;
  const int a_base = (wm * 64 + fr) * 8;
  const int b_base = (wn * 32 + fr) * 8;
  const int kx0 = fc ^ frx;            // k-step 0
  const int kx1 = (4 + fc) ^ frx;      // k-step 1

  f32x4 acc[8][4] = {};
  short8 af[4][2];
  short8 bv[2][2];

  // prologue ring priming (issue order = vmcnt retirement order):
  // A0(0), B0(0), B1(0), A1(0), A0(1), B0(1)  -- 6 halves, 12 loads
  STAGEH(As, Asrc0);               // A0(0) buf0
  STAGEH(Bs, Bsrc0);               // B0(0)
  STAGEH(Bs + 1024, Bsrc1);        // B1(0)
  STAGEH(As + 1024, Asrc1);        // A1(0)
  STAGEH(As + 2048, Asrc0 + 64);   // A0(1) buf1
  STAGEH(Bs + 2048, Bsrc0 + 64);   // B0(1)
  asm volatile("s_waitcnt vmcnt(8)" ::: "memory");  // A0(0),B0(0) landed
  __builtin_amdgcn_sched_barrier(0);
  __builtin_amdgcn_s_barrier();

  for (int kt = 0; kt < NT; ++kt) {
    const int cur = kt & 1;
    const short8* ASb = As + cur * 2048;
    const short8* BSb = Bs + cur * 2048;
    short8* Anx = As + (cur ^ 1) * 2048;   // buf of tile kt+1
    short8* Bnx = Bs + (cur ^ 1) * 2048;
    short8* Asame = As + cur * 2048;       // buf of tile kt+2 (== cur)
    short8* Bsame = Bs + cur * 2048;
    const bool p1ok = (kt + 1 < NT);
    const bool p2ok = (kt + 2 < NT);

    // ---- P1: Q(0,0); stage B1(kt+1) [slot died P4(kt-1)] ----
    WAIT_VM6;
    LOADAF(0);
    LOADBV(0);
    if (p1ok) STAGEH(Bnx + 1024, Bsrc1 + (size_t)(kt + 1) * 64);
    __builtin_amdgcn_s_barrier();
    WAIT_LGKM0;
    MFMAQ(0, 0);
    __builtin_amdgcn_s_barrier();

    // ---- P2: Q(0,1); stage A1(kt+1) [slot's reads done P3(kt-1)] ----
    WAIT_VM6;
    LOADBV(1);
    if (p1ok) STAGEH(Anx + 1024, Asrc1 + (size_t)(kt + 1) * 64);
    __builtin_amdgcn_s_barrier();
    WAIT_LGKM0;
    MFMAQ(0, 1);
    __builtin_amdgcn_s_barrier();

    // ---- P3: Q(1,0); stage A0(kt+2) [A0(kt) died P2] ----
    WAIT_VM6;
    LOADAF(1);
    LOADBV(0);
    if (p2ok) STAGEH(Asame, Asrc0 + (size_t)(kt + 2) * 64);
    __builtin_amdgcn_s_barrier();
    WAIT_LGKM0;
    MFMAQ(1, 0);
    __builtin_amdgcn_s_barrier();

    // ---- P4: Q(1,1); stage B0(kt+2) [B0(kt) died P3] ----
    WAIT_VM6;
    LOADBV(1);
    if (p2ok) STAGEH(Bsame, Bsrc0 + (size_t)(kt + 2) * 64);
    __builtin_amdgcn_s_barrier();
    WAIT_LGKM0;
    MFMAQ(1, 1);
    __builtin_amdgcn_s_barrier();
  }

  // epilogue: C/D layout col=lane&15, row=(lane>>4)*4+reg
  const int rr = (lane >> 4) * 4;
#pragma unroll
  for (int cb = 0; cb < 2; ++cb)
#pragma unroll
    for (int ni = 0; ni < 2; ++ni) {
      const int gn = n0 + cb * 128 + wn * 32 + ni * 16 + fr;
      const float bvv = bias[gn];
#pragma unroll
      for (int rb = 0; rb < 2; ++rb)
#pragma unroll
        for (int mi = 0; mi < 4; ++mi) {
          const int gm = m0 + rb * 128 + wm * 64 + mi * 16 + rr;
#pragma unroll
          for (int r = 0; r < 4; ++r)
            C[(size_t)(gm + r) * N_DIM + gn] = acc[rb * 4 + mi][cb * 2 + ni][r] + bvv;
        }
    }
}

extern "C" void kernel_launch(void* const* d_in, const int* in_sizes, int n_in,
                              void* d_out, int out_size, void* d_ws, size_t ws_size,
                              hipStream_t stream) {
  const float* x = (const float*)d_in[0];
  const int* wq = (const int*)d_in[1];
  const float* sc = (const float*)d_in[2];
  const float* zr = (const float*)d_in[3];
  const float* bias = (const float*)d_in[4];
  float* out = (float*)d_out;

  unsigned short* xb = (unsigned short*)d_ws;
  unsigned short* wt = (unsigned short*)((char*)d_ws + (size_t)M_DIM * K_DIM * 2);

  prep_kernel<<<dim3(3072), dim3(256), 0, stream>>>(x, xb, wq, sc, zr, wt);
  gemm_bt_kernel<<<dim3(256), dim3(512), 0, stream>>>(xb, wt, bias, out);
}

// Round 4
// 260.184 us; speedup vs baseline: 1.0362x; 1.0104x over previous
//
#include <hip/hip_runtime.h>
#include <stdint.h>

// out[M,N] = x[M,K] @ dequant(W_q_packed)[K,N] + bias[N]
// M=N=K=4096, 4-bit nibbles packed 8/int32 along K, GROUP=128.
// R9: faithful port of the verified 256^2 8-phase template (m201/m204 class).
// 256x256 tile, BK=64, 8 waves (2Mx4N), per-wave 128x64 out. 4 phases/K-tile,
// quadrant Gray-order (0,0)->(0,1)->(1,1)->(1,0) with frag reg reuse
// (reads 12/4/8/4 per phase = 28/wave/K-tile). Per phase: ds_read subtile ->
// stage ONE half-tile (2 global_load_lds) -> [P1: lgkmcnt(8)] -> barrier ->
// lgkmcnt(0) -> setprio(1) 16xMFMA setprio(0) -> barrier. ONE vmcnt(6) per
// K-tile (end P4, before publish barrier): retires through B0(kt+1), leaves
// exactly 3 half-tiles (6 loads) in flight across the barrier. Stage stagger
// matches slot deaths: P1:B0(kt+1), P2:A0(kt+2), P3:B1(kt+2), P4:A1(kt+2);
// every stage >=1 full phase after its slot's last read (WAR safe), every
// read >=4 enforced phases after its stage (RAW safe). Epilogue drain 6->0.
// LDS 128KB dbuf, zero-conflict XOR-cell layout (cell=row*8+(kc^(row&7)),
// pre-swizzled global source). XCD swizzle: each XCD owns 2 B-panels.

#define M_DIM 4096
#define N_DIM 4096
#define K_DIM 4096
#define NT (K_DIM / 64)

typedef __attribute__((ext_vector_type(8))) short short8;
typedef __attribute__((ext_vector_type(4))) float f32x4;

__device__ __forceinline__ unsigned short f2bf(float f) {
  uint32_t u = __builtin_bit_cast(uint32_t, f);
  u += 0x7fffu + ((u >> 16) & 1u);   // round-to-nearest-even
  return (unsigned short)(u >> 16);
}

// ---------- kernel 1: fused prep (unchanged) ----------
__global__ __launch_bounds__(256) void prep_kernel(const float* __restrict__ x,
                                                   unsigned short* __restrict__ xb,
                                                   const int* __restrict__ Wq,
                                                   const float* __restrict__ scales,
                                                   const float* __restrict__ zeros,
                                                   unsigned short* __restrict__ wt) {
  __shared__ uint4 Ts[32 * 64];  // 32 KB (dequant slice only)
  const int tid = threadIdx.x;
  if (blockIdx.x < 2048) {
    const int total = (M_DIM * K_DIM) / 8;   // 2M ushort8
    const float4* x4 = (const float4*)x;
    uint4* o8 = (uint4*)xb;
#pragma unroll
    for (int p = 0; p < 4; ++p) {
      int i = (p * 2048 + blockIdx.x) * 256 + tid;
      if (i < total) {
        float4 a = x4[2 * i], b = x4[2 * i + 1];
        uint4 o;
        o.x = (uint32_t)f2bf(a.x) | ((uint32_t)f2bf(a.y) << 16);
        o.y = (uint32_t)f2bf(a.z) | ((uint32_t)f2bf(a.w) << 16);
        o.z = (uint32_t)f2bf(b.x) | ((uint32_t)f2bf(b.y) << 16);
        o.w = (uint32_t)f2bf(b.z) | ((uint32_t)f2bf(b.w) << 16);
        o8[i] = o;
      }
    }
    return;
  }
  const int blk = blockIdx.x - 2048;
  const int n0 = (blk & 127) * 32;        // N/32 = 128 tiles
  const int gk0 = (blk >> 7) * 64;        // (K/8)/64 = 8 tiles

#pragma unroll
  for (int p = 0; p < 8; ++p) {
    int e = p * 256 + tid;
    int n_l = e & 31;
    int gk_l = e >> 5;
    int gk = gk0 + gk_l;
    int n = n0 + n_l;
    int g = gk >> 4;                // group = (gk*8)/128
    uint32_t q = (uint32_t)Wq[gk * N_DIM + n];
    float s = scales[g * N_DIM + n];
    float z = zeros[g * N_DIM + n];
    unsigned short b[8];
#pragma unroll
    for (int j = 0; j < 8; ++j) {
      float f = ((float)((q >> (4 * j)) & 15u) - z) * s;
      b[j] = f2bf(f);
    }
    uint4 cell;
    cell.x = (uint32_t)b[0] | ((uint32_t)b[1] << 16);
    cell.y = (uint32_t)b[2] | ((uint32_t)b[3] << 16);
    cell.z = (uint32_t)b[4] | ((uint32_t)b[5] << 16);
    cell.w = (uint32_t)b[6] | ((uint32_t)b[7] << 16);
    Ts[n_l * 64 + (gk_l ^ (n_l & 7))] = cell;
  }
  __syncthreads();
  uint4* dst = (uint4*)wt;
#pragma unroll
  for (int p = 0; p < 8; ++p) {
    int n_l = p * 4 + (tid >> 6);
    int gk_l = tid & 63;
    uint4 cell = Ts[n_l * 64 + (gk_l ^ (n_l & 7))];
    dst[(size_t)(n0 + n_l) * (K_DIM / 8) + (gk0 + gk_l)] = cell;
  }
}

// ---------- kernel 2: bf16 GEMM, C = A @ Bt^T + bias ----------

// stage one 128-row half-tile: 2 collective global_load_lds per thread
#define STAGEH(DST, SRC)                                                        \
  {                                                                             \
    __builtin_amdgcn_global_load_lds(                                           \
        (const __attribute__((address_space(1))) void*)(SRC),                   \
        (__attribute__((address_space(3))) void*)((DST) + tid), 16, 0, 0);      \
    __builtin_amdgcn_global_load_lds(                                           \
        (const __attribute__((address_space(1))) void*)((SRC) + 64 * K_DIM),    \
        (__attribute__((address_space(3))) void*)((DST) + tid + 512), 16, 0, 0);\
  }

// af: 4 row-frags of half RB (rows RB*128 + wm*64 + mi*16 + fr)
#define LOADAF(RB)                                                              \
  {                                                                             \
    _Pragma("unroll") for (int mi = 0; mi < 4; ++mi) {                          \
      af[mi][0] = ASb[(RB)*1024 + a_base + mi * 128 + kx0];                     \
      af[mi][1] = ASb[(RB)*1024 + a_base + mi * 128 + kx1];                     \
    }                                                                           \
  }

// bv: 2 col-frags of half CB (rows CB*128 + wn*32 + ni*16 + fr)
#define LOADBV(CB)                                                              \
  {                                                                             \
    _Pragma("unroll") for (int ni = 0; ni < 2; ++ni) {                          \
      bv[ni][0] = BSb[(CB)*1024 + b_base + ni * 128 + kx0];                     \
      bv[ni][1] = BSb[(CB)*1024 + b_base + ni * 128 + kx1];                     \
    }                                                                           \
  }

#define MFMAQ(RB, CB)                                                           \
  {                                                                             \
    __builtin_amdgcn_s_setprio(1);                                              \
    _Pragma("unroll") for (int mi = 0; mi < 4; ++mi)                            \
        _Pragma("unroll") for (int ni = 0; ni < 2; ++ni) {                      \
      acc[(RB)*4 + mi][(CB)*2 + ni] = __builtin_amdgcn_mfma_f32_16x16x32_bf16(  \
          af[mi][0], bv[ni][0], acc[(RB)*4 + mi][(CB)*2 + ni], 0, 0, 0);        \
      acc[(RB)*4 + mi][(CB)*2 + ni] = __builtin_amdgcn_mfma_f32_16x16x32_bf16(  \
          af[mi][1], bv[ni][1], acc[(RB)*4 + mi][(CB)*2 + ni], 0, 0, 0);        \
    }                                                                           \
    __builtin_amdgcn_s_setprio(0);                                              \
  }

#define WAIT_LGKM0                                         \
  asm volatile("s_waitcnt lgkmcnt(0)" ::: "memory");       \
  __builtin_amdgcn_sched_barrier(0);

#define EW6                                                \
  asm volatile("s_waitcnt vmcnt(6)" ::: "memory");         \
  __builtin_amdgcn_sched_barrier(0)

#define EW0                                                \
  asm volatile("s_waitcnt vmcnt(0)" ::: "memory");         \
  __builtin_amdgcn_sched_barrier(0)

// one K-tile: 4 phases, Gray quadrant order, stages S1..S4, end wait EW
#define KTILE(S1, S2, S3, S4, EW)                          \
  {                                                        \
    /* P1: Q(0,0) -- 12 ds_reads */                        \
    LOADAF(0);                                             \
    LOADBV(0);                                             \
    S1;                                                    \
    asm volatile("s_waitcnt lgkmcnt(8)" ::: "memory");     \
    __builtin_amdgcn_sched_barrier(0);                     \
    __builtin_amdgcn_s_barrier();                          \
    WAIT_LGKM0;                                            \
    MFMAQ(0, 0);                                           \
    __builtin_amdgcn_s_barrier();                          \
    /* P2: Q(0,1) -- af held, 4 ds_reads */                \
    LOADBV(1);                                             \
    S2;                                                    \
    __builtin_amdgcn_s_barrier();                          \
    WAIT_LGKM0;                                            \
    MFMAQ(0, 1);                                           \
    __builtin_amdgcn_s_barrier();                          \
    /* P3: Q(1,1) -- bv held, 8 ds_reads */                \
    LOADAF(1);                                             \
    S3;                                                    \
    __builtin_amdgcn_s_barrier();                          \
    WAIT_LGKM0;                                            \
    MFMAQ(1, 1);                                           \
    __builtin_amdgcn_s_barrier();                          \
    /* P4: Q(1,0) -- af held, 4 ds_reads; tile-end wait */ \
    LOADBV(0);                                             \
    S4;                                                    \
    __builtin_amdgcn_s_barrier();                          \
    WAIT_LGKM0;                                            \
    MFMAQ(1, 0);                                           \
    EW;                                                    \
    __builtin_amdgcn_s_barrier();                          \
  }

__global__ __launch_bounds__(512, 2) void gemm_bt_kernel(
    const unsigned short* __restrict__ A, const unsigned short* __restrict__ Bt,
    const float* __restrict__ bias, float* __restrict__ C) {
  __shared__ short8 As[2 * 2048];  // 64 KB (2 buffers x 256 rows x 8 cells)
  __shared__ short8 Bs[2 * 2048];  // 64 KB

  const int tid = threadIdx.x;
  const int lane = tid & 63;
  const int w = tid >> 6;      // 0..7
  const int wm = w >> 2;       // 0..1
  const int wn = w & 3;        // 0..3

  // XCD swizzle: 256 blocks; xcd owns nt in {2*xcd, 2*xcd+1} (4MB of B = L2)
  const int b = blockIdx.x;
  const int xcd = b & 7;
  const int loc = b >> 3;              // 0..31
  const int nt = xcd * 2 + (loc & 1);  // 0..15
  const int mt = loc >> 1;             // 0..15
  const int m0 = mt * 256;
  const int n0 = nt * 256;

  // staging addressing: thread covers cells tid (+512) within a half
  const int srow = tid >> 3;                       // local row 0..63 (+64 for j=1)
  const int skc = (tid & 7) ^ (srow & 7);          // row&7 invariant across +64
  const unsigned short* Asrc0 = A + (size_t)(m0 + srow) * K_DIM + skc * 8;
  const unsigned short* Asrc1 = Asrc0 + (size_t)128 * K_DIM;
  const unsigned short* Bsrc0 = Bt + (size_t)(n0 + srow) * K_DIM + skc * 8;
  const unsigned short* Bsrc1 = Bsrc0 + (size_t)128 * K_DIM;

  // fragment read addressing
  const int fr = lane & 15;            // row-low (A) / col-low (B)
  const int fc = lane >> 4;            // k-quarter 0..3
  const int frx = fr & 7;
  const int a_base = (wm * 64 + fr) * 8;
  const int b_base = (wn * 32 + fr) * 8;
  const int kx0 = fc ^ frx;            // k-step 0
  const int kx1 = (4 + fc) ^ frx;      // k-step 1

  f32x4 acc[8][4] = {};
  short8 af[4][2];
  short8 bv[2][2];

  // prologue: 7 halves (14 loads) in steady-state issue order, then vmcnt(6)
  // retires tile 0's 4 halves, leaving A0(1),B1(1),A1(1) = 6 loads in flight.
  STAGEH(As, Asrc0);               // A0(0) buf0
  STAGEH(Bs, Bsrc0);               // B0(0)
  STAGEH(Bs + 1024, Bsrc1);        // B1(0)
  STAGEH(As + 1024, Asrc1);        // A1(0)
  STAGEH(As + 2048, Asrc0 + 64);   // A0(1) buf1
  STAGEH(Bs + 3072, Bsrc1 + 64);   // B1(1)
  STAGEH(As + 3072, Asrc1 + 64);   // A1(1)
  EW6;
  __builtin_amdgcn_s_barrier();

  // main loop: kt in [0, NT-2); unconditional stages
  for (int kt = 0; kt < NT - 2; ++kt) {
    const int cur = kt & 1;
    const short8* ASb = As + cur * 2048;
    const short8* BSb = Bs + cur * 2048;
    short8* Adst0 = As + cur * 2048;                  // A0(kt+2) slot (same buf)
    short8* Adst1 = As + cur * 2048 + 1024;           // A1(kt+2)
    short8* Bdst0 = Bs + ((kt + 1) & 1) * 2048;       // B0(kt+1) slot (other buf)
    short8* Bdst1 = Bs + cur * 2048 + 1024;           // B1(kt+2)
    const size_t k1 = (size_t)(kt + 1) * 64;
    const size_t k2 = (size_t)(kt + 2) * 64;

    KTILE(STAGEH(Bdst0, Bsrc0 + k1),
          STAGEH(Adst0, Asrc0 + k2),
          STAGEH(Bdst1, Bsrc1 + k2),
          STAGEH(Adst1, Asrc1 + k2),
          EW6);
  }

  // kt = NT-2 (cur=0): stage only B0(NT-1); drain to 0 at tile end
  {
    const short8* ASb = As;
    const short8* BSb = Bs;
    short8* Bdst0 = Bs + 2048;
    const size_t k1 = (size_t)(NT - 1) * 64;
    KTILE(STAGEH(Bdst0, Bsrc0 + k1), (void)0, (void)0, (void)0, EW0);
  }

  // kt = NT-1 (cur=1): no stages, no vm waits
  {
    const short8* ASb = As + 2048;
    const short8* BSb = Bs + 2048;
    KTILE((void)0, (void)0, (void)0, (void)0, (void)0);
  }

  // epilogue: C/D layout col=lane&15, row=(lane>>4)*4+reg
  const int rr = (lane >> 4) * 4;
#pragma unroll
  for (int cb = 0; cb < 2; ++cb)
#pragma unroll
    for (int ni = 0; ni < 2; ++ni) {
      const int gn = n0 + cb * 128 + wn * 32 + ni * 16 + fr;
      const float bvv = bias[gn];
#pragma unroll
      for (int rb = 0; rb < 2; ++rb)
#pragma unroll
        for (int mi = 0; mi < 4; ++mi) {
          const int gm = m0 + rb * 128 + wm * 64 + mi * 16 + rr;
#pragma unroll
          for (int r = 0; r < 4; ++r)
            C[(size_t)(gm + r) * N_DIM + gn] = acc[rb * 4 + mi][cb * 2 + ni][r] + bvv;
        }
    }
}

extern "C" void kernel_launch(void* const* d_in, const int* in_sizes, int n_in,
                              void* d_out, int out_size, void* d_ws, size_t ws_size,
                              hipStream_t stream) {
  const float* x = (const float*)d_in[0];
  const int* wq = (const int*)d_in[1];
  const float* sc = (const float*)d_in[2];
  const float* zr = (const float*)d_in[3];
  const float* bias = (const float*)d_in[4];
  float* out = (float*)d_out;

  unsigned short* xb = (unsigned short*)d_ws;
  unsigned short* wt = (unsigned short*)((char*)d_ws + (size_t)M_DIM * K_DIM * 2);

  prep_kernel<<<dim3(3072), dim3(256), 0, stream>>>(x, xb, wq, sc, zr, wt);
  gemm_bt_kernel<<<dim3(256), dim3(512), 0, stream>>>(xb, wt, bias, out);
}

// Round 7
// 259.097 us; speedup vs baseline: 1.0405x; 1.0042x over previous
//
#include <hip/hip_runtime.h>
#include <stdint.h>

// out[M,N] = x[M,K] @ dequant(W_q_packed)[K,N] + bias[N]
// M=N=K=4096, 4-bit nibbles packed 8/int32 along K, GROUP=128.
// R12: read-AHEAD pipeline (R10 hypothesis), de-risked: + tile-end barrier
// (bounds wave skew to <1 tile; R10's free-run was the only novel discipline
// vs the R6-R9 kernels that ran fine - and R10/R11 both died in "container
// failed twice" with no kernel verdict).
// Hypothesis: R6-R9 all ~149us/38% MfmaUtil because every phase's lgkmcnt(0)
// waits on ds_reads issued in the SAME phase -> LDS burst and MFMA cluster
// serialize. Fix: fragment reads issued >=1 MFMA cluster before consumer ->
// compiler emits counted lgkm waits with a full cluster (~128cy) of cover.
// BK=32 tiles, frag dbuf in regs (afP/afQ + bv0a/bv0b/bvQ = 56 VGPR),
// 4-deep LDS ring (4x16KBx2 = 128KB), stage lead 2 tiles, per tile: ONE
// {vmcnt(2); barrier} publish (mid-tile) + ONE skew barrier (tile end).
// Read schedule per tile T (Gray quadrants (0,0)(0,1)(1,1)(1,0)):
//   P1: rd af1(T)->afQ [consume P3]      P3: rd bv0(T+1)->bv0_next [P1']
//   P4: rd af0(T+1)->afP, bv1(T+1)->bvQ [P1'/P2']
// vmcnt ledger: steady state at mid-tile VM2, outstanding = {A0(T+2),A1(T+2)}
// after retiring through B1(T+1); prologue vmcnt(4) retires tile 0; peel
// tiles 126 (VM0) / 127 (none). WAR: stage into buf (T+2)&3 at tile T P1 is
// ordered after tile T-1's end barrier, long after buf's last reads (tile
// T-2) were consumed. RAW: buf(T+1) published mid-tile T, first read P3(T).
// LDS cell swizzle for 4-cell rows: kc = j ^ ((row>>1)&3) -> 2 lanes/bank.
// XCD swizzle: each XCD owns 2 B-panels (4MB = its L2), sweeps 16 M-tiles.

#define M_DIM 4096
#define N_DIM 4096
#define K_DIM 4096

typedef __attribute__((ext_vector_type(8))) short short8;
typedef __attribute__((ext_vector_type(4))) float f32x4;

__device__ __forceinline__ unsigned short f2bf(float f) {
  uint32_t u = __builtin_bit_cast(uint32_t, f);
  u += 0x7fffu + ((u >> 16) & 1u);   // round-to-nearest-even
  return (unsigned short)(u >> 16);
}

// ---------- kernel 1: fused prep (unchanged) ----------
__global__ __launch_bounds__(256) void prep_kernel(const float* __restrict__ x,
                                                   unsigned short* __restrict__ xb,
                                                   const int* __restrict__ Wq,
                                                   const float* __restrict__ scales,
                                                   const float* __restrict__ zeros,
                                                   unsigned short* __restrict__ wt) {
  __shared__ uint4 Ts[32 * 64];  // 32 KB (dequant slice only)
  const int tid = threadIdx.x;
  if (blockIdx.x < 2048) {
    const int total = (M_DIM * K_DIM) / 8;   // 2M ushort8
    const float4* x4 = (const float4*)x;
    uint4* o8 = (uint4*)xb;
#pragma unroll
    for (int p = 0; p < 4; ++p) {
      int i = (p * 2048 + blockIdx.x) * 256 + tid;
      if (i < total) {
        float4 a = x4[2 * i], b = x4[2 * i + 1];
        uint4 o;
        o.x = (uint32_t)f2bf(a.x) | ((uint32_t)f2bf(a.y) << 16);
        o.y = (uint32_t)f2bf(a.z) | ((uint32_t)f2bf(a.w) << 16);
        o.z = (uint32_t)f2bf(b.x) | ((uint32_t)f2bf(b.y) << 16);
        o.w = (uint32_t)f2bf(b.z) | ((uint32_t)f2bf(b.w) << 16);
        o8[i] = o;
      }
    }
    return;
  }
  const int blk = blockIdx.x - 2048;
  const int n0 = (blk & 127) * 32;        // N/32 = 128 tiles
  const int gk0 = (blk >> 7) * 64;        // (K/8)/64 = 8 tiles

#pragma unroll
  for (int p = 0; p < 8; ++p) {
    int e = p * 256 + tid;
    int n_l = e & 31;
    int gk_l = e >> 5;
    int gk = gk0 + gk_l;
    int n = n0 + n_l;
    int g = gk >> 4;                // group = (gk*8)/128
    uint32_t q = (uint32_t)Wq[gk * N_DIM + n];
    float s = scales[g * N_DIM + n];
    float z = zeros[g * N_DIM + n];
    unsigned short b[8];
#pragma unroll
    for (int j = 0; j < 8; ++j) {
      float f = ((float)((q >> (4 * j)) & 15u) - z) * s;
      b[j] = f2bf(f);
    }
    uint4 cell;
    cell.x = (uint32_t)b[0] | ((uint32_t)b[1] << 16);
    cell.y = (uint32_t)b[2] | ((uint32_t)b[3] << 16);
    cell.z = (uint32_t)b[4] | ((uint32_t)b[5] << 16);
    cell.w = (uint32_t)b[6] | ((uint32_t)b[7] << 16);
    Ts[n_l * 64 + (gk_l ^ (n_l & 7))] = cell;
  }
  __syncthreads();
  uint4* dst = (uint4*)wt;
#pragma unroll
  for (int p = 0; p < 8; ++p) {
    int n_l = p * 4 + (tid >> 6);
    int gk_l = tid & 63;
    uint4 cell = Ts[n_l * 64 + (gk_l ^ (n_l & 7))];
    dst[(size_t)(n0 + n_l) * (K_DIM / 8) + (gk0 + gk_l)] = cell;
  }
}

// ---------- kernel 2: bf16 GEMM, C = A @ Bt^T + bias ----------
// 256x256 tile, 8 waves (2Mx4N), per-wave 128x64 out = acc[8][4].
// LDS: 4-ring of BK=32 buffers; buffer = 256 rows x 4 cells of 16B;
// cell(row, j) holds logical kc = j ^ ((row>>1)&3).

#define ASBUF(T) (As + ((T) & 3) * 1024)
#define BSBUF(T) (Bs + ((T) & 3) * 1024)
#define ASRC(T) (Asrc + (size_t)(T) * 32)
#define BSRC(T) (Bsrc + (size_t)(T) * 32)

#define GLDS(DST, SRC)                                                          \
  __builtin_amdgcn_global_load_lds(                                             \
      (const __attribute__((address_space(1))) void*)(SRC),                     \
      (__attribute__((address_space(3))) void*)(DST), 16, 0, 0)

#define RD_AF(T, DST, RB)                                                       \
  {                                                                             \
    _Pragma("unroll") for (int mi = 0; mi < 4; ++mi)                            \
        DST[mi] = ASBUF(T)[a_b + (RB) * 512 + mi * 64];                         \
  }

#define RD_BV(T, DST, CB)                                                       \
  {                                                                             \
    _Pragma("unroll") for (int ni = 0; ni < 2; ++ni)                            \
        DST[ni] = BSBUF(T)[b_b + (CB) * 512 + ni * 64];                         \
  }

#define MFMAQ(AF, BV, RB, CB)                                                   \
  {                                                                             \
    __builtin_amdgcn_s_setprio(1);                                              \
    _Pragma("unroll") for (int mi = 0; mi < 4; ++mi)                            \
        _Pragma("unroll") for (int ni = 0; ni < 2; ++ni)                        \
            acc[(RB) * 4 + mi][(CB) * 2 + ni] =                                 \
                __builtin_amdgcn_mfma_f32_16x16x32_bf16(                        \
                    AF[mi], BV[ni], acc[(RB) * 4 + mi][(CB) * 2 + ni], 0, 0, 0);\
    __builtin_amdgcn_s_setprio(0);                                              \
  }

#define SB0 __builtin_amdgcn_sched_barrier(0)
#define VM2 asm volatile("s_waitcnt vmcnt(2)" ::: "memory")
#define VM0 asm volatile("s_waitcnt vmcnt(0)" ::: "memory")

// one BK=32 K-tile: 4 quadrant clusters, reads one cluster ahead,
// publish {VMW; barrier} between P2 and P3, skew barrier at tile end.
#define TILE32(T, BV0C, BV0N, STG, RDN, VMW)                                    \
  {                                                                             \
    /* P1: rd af1(T) [for P3]; stage A0(T+2); MFMA Q(0,0) */                    \
    RD_AF((T), afQ, 1);                                                         \
    if (STG) GLDS(ASBUF((T) + 2) + tid, ASRC((T) + 2));                         \
    SB0;                                                                        \
    MFMAQ(afP, BV0C, 0, 0);                                                     \
    SB0;                                                                        \
    /* P2: stage A1(T+2); MFMA Q(0,1); publish tile T+1 */                      \
    if (STG) GLDS(ASBUF((T) + 2) + tid + 512, ASRC((T) + 2) + (size_t)128 * K_DIM); \
    SB0;                                                                        \
    MFMAQ(afP, bvQ, 0, 1);                                                      \
    SB0;                                                                        \
    VMW;                                                                        \
    SB0;                                                                        \
    __builtin_amdgcn_s_barrier();                                               \
    SB0;                                                                        \
    /* P3: rd bv0(T+1) [for P1']; stage B0(T+2); MFMA Q(1,1) */                 \
    if (RDN) RD_BV((T) + 1, BV0N, 0);                                           \
    if (STG) GLDS(BSBUF((T) + 2) + tid, BSRC((T) + 2));                         \
    SB0;                                                                        \
    MFMAQ(afQ, bvQ, 1, 1);                                                      \
    SB0;                                                                        \
    /* P4: rd af0,bv1(T+1) [for P1'/P2']; stage B1(T+2); MFMA Q(1,0) */         \
    if (RDN) { RD_AF((T) + 1, afP, 0); RD_BV((T) + 1, bvQ, 1); }                \
    if (STG) GLDS(BSBUF((T) + 2) + tid + 512, BSRC((T) + 2) + (size_t)128 * K_DIM); \
    SB0;                                                                        \
    MFMAQ(afQ, BV0C, 1, 0);                                                     \
    SB0;                                                                        \
    __builtin_amdgcn_s_barrier(); /* tile-end skew bound */                     \
    SB0;                                                                        \
  }

__global__ __launch_bounds__(512, 2) void gemm_bt_kernel(
    const unsigned short* __restrict__ A, const unsigned short* __restrict__ Bt,
    const float* __restrict__ bias, float* __restrict__ C) {
  __shared__ short8 As[4 * 1024];  // 64 KB: 4-ring of 256x32 bf16
  __shared__ short8 Bs[4 * 1024];  // 64 KB

  const int tid = threadIdx.x;
  const int lane = tid & 63;
  const int w = tid >> 6;      // 0..7
  const int wm = w >> 2;       // 0..1
  const int wn = w & 3;        // 0..3

  // XCD swizzle: 256 blocks; xcd owns nt in {2*xcd, 2*xcd+1} (4MB of B = L2)
  const int b = blockIdx.x;
  const int xcd = b & 7;
  const int loc = b >> 3;              // 0..31
  const int nt = xcd * 2 + (loc & 1);  // 0..15
  const int mt = loc >> 1;             // 0..15
  const int m0 = mt * 256;
  const int n0 = nt * 256;

  // staging: thread covers cells tid (rows 0..127) and tid+512 (rows 128..255)
  const int srow = tid >> 2;                        // 0..127
  const int skc = (tid & 3) ^ ((srow >> 1) & 3);    // swizzle inv under +128
  const unsigned short* Asrc = A + (size_t)(m0 + srow) * K_DIM + skc * 8;
  const unsigned short* Bsrc = Bt + (size_t)(n0 + srow) * K_DIM + skc * 8;

  // fragment read addressing: idx = row*4 + (fc ^ ((fr>>1)&3))
  const int fr = lane & 15;            // row-low (A) / col-low (B)
  const int fc = lane >> 4;            // k-quarter 0..3 (8B units within 32k)
  const int kxs = fc ^ ((fr >> 1) & 3);
  const int a_b = (wm * 64 + fr) * 4 + kxs;
  const int b_b = (wn * 32 + fr) * 4 + kxs;

  f32x4 acc[8][4] = {};
  short8 afP[4], afQ[4];         // af ping-pong (af0 / af1 of current tile)
  short8 bv0a[2], bv0b[2];       // bv0 by tile parity
  short8 bvQ[2];                 // bv1 (rewritten each tile at P4)

  // prologue: stage tiles 0,1; wait tile0 (vmcnt(4) leaves tile1's 4); reads
  GLDS(ASBUF(0) + tid, ASRC(0));
  GLDS(ASBUF(0) + tid + 512, ASRC(0) + (size_t)128 * K_DIM);
  GLDS(BSBUF(0) + tid, BSRC(0));
  GLDS(BSBUF(0) + tid + 512, BSRC(0) + (size_t)128 * K_DIM);
  GLDS(ASBUF(1) + tid, ASRC(1));
  GLDS(ASBUF(1) + tid + 512, ASRC(1) + (size_t)128 * K_DIM);
  GLDS(BSBUF(1) + tid, BSRC(1));
  GLDS(BSBUF(1) + tid + 512, BSRC(1) + (size_t)128 * K_DIM);
  asm volatile("s_waitcnt vmcnt(4)" ::: "memory");
  SB0;
  __builtin_amdgcn_s_barrier();
  SB0;
  // pre-reads for tile 0 entry (mimic P3/P4 of a virtual tile -1)
  RD_BV(0, bv0a, 0);
  RD_AF(0, afP, 0);
  RD_BV(0, bvQ, 1);
  SB0;

  // main loop: tiles 0..125 stage tiles 2..127
  for (int t = 0; t < 126; t += 2) {
    TILE32(t, bv0a, bv0b, 1, 1, VM2);
    TILE32(t + 1, bv0b, bv0a, 1, 1, VM2);
  }
  // peel: tile 126 (no stage; drain), tile 127 (no stage, no next reads)
  TILE32(126, bv0a, bv0b, 0, 1, VM0);
  TILE32(127, bv0b, bv0a, 0, 0, (void)0);

  // epilogue: C/D layout col=lane&15, row=(lane>>4)*4+reg
  const int rr = (lane >> 4) * 4;
#pragma unroll
  for (int cb = 0; cb < 2; ++cb)
#pragma unroll
    for (int ni = 0; ni < 2; ++ni) {
      const int gn = n0 + cb * 128 + wn * 32 + ni * 16 + fr;
      const float bvv = bias[gn];
#pragma unroll
      for (int rb = 0; rb < 2; ++rb)
#pragma unroll
        for (int mi = 0; mi < 4; ++mi) {
          const int gm = m0 + rb * 128 + wm * 64 + mi * 16 + rr;
#pragma unroll
          for (int r = 0; r < 4; ++r)
            C[(size_t)(gm + r) * N_DIM + gn] = acc[rb * 4 + mi][cb * 2 + ni][r] + bvv;
        }
    }
}

extern "C" void kernel_launch(void* const* d_in, const int* in_sizes, int n_in,
                              void* d_out, int out_size, void* d_ws, size_t ws_size,
                              hipStream_t stream) {
  const float* x = (const float*)d_in[0];
  const int* wq = (const int*)d_in[1];
  const float* sc = (const float*)d_in[2];
  const float* zr = (const float*)d_in[3];
  const float* bias = (const float*)d_in[4];
  float* out = (float*)d_out;

  unsigned short* xb = (unsigned short*)d_ws;
  unsigned short* wt = (unsigned short*)((char*)d_ws + (size_t)M_DIM * K_DIM * 2);

  prep_kernel<<<dim3(3072), dim3(256), 0, stream>>>(x, xb, wq, sc, zr, wt);
  gemm_bt_kernel<<<dim3(256), dim3(512), 0, stream>>>(xb, wt, bias, out);
}